// Round 4
// baseline (282.854 us; speedup 1.0000x reference)
//
#include <hip/hip_runtime.h>

#define NC 91
#define NBIN 182          // bins 0..90 = union counts, 91..181 = intersection counts
#define NB 32
#define HW (1024 * 1024)
#define NT 256            // threads per block
#define PPT 64            // pixels per thread (max per-bin per-thread = 128 < 255, u8 safe)
#define PIX_PER_BLOCK (NT * PPT)   // 16384
#define ROWS 46           // ceil(NBIN/4) dword-rows; each row = 256 threads * 4B = 1024 B

// Conflict-free-by-construction layout:
//   byte addr(bin, tid) = (bin/4)*1024 + tid*4 + (bin%4)
//   bank = (addr/4) % 32 = tid % 32  -> independent of bin; 2-way lane alias only (free).

__global__ __launch_bounds__(256) void hist_kernel(const int* __restrict__ x,
                                                   const int* __restrict__ t,
                                                   int* __restrict__ g_hist) {
    __shared__ unsigned char s_h[ROWS * 1024];  // 47,104 B

    const int tid = threadIdx.x;

    // zero-init (11,776 dwords)
    {
        unsigned int* p = (unsigned int*)s_h;
        for (int i = tid; i < ROWS * 1024 / 4; i += NT) p[i] = 0u;
    }
    __syncthreads();

    const int lanebase = tid << 2;   // bits 2..9; disjoint from row bits (>=10) and byte bits (0..1)

    const int b = blockIdx.y;
    const long base = (long)b * HW + (long)blockIdx.x * PIX_PER_BLOCK;
    const int4* __restrict__ x4 = (const int4*)(x + base);
    const int4* __restrict__ t4 = (const int4*)(t + base);

#pragma unroll 4
    for (int i = 0; i < PPT / 4; ++i) {
        int4 xv = x4[i * NT + tid];
        int4 tv = t4[i * NT + tid];
        // increment 1: union[x]; increment 2: inter[x] if match else union[t]
        int u0 = xv.x, u1 = xv.y, u2 = xv.z, u3 = xv.w;
        int v0 = (xv.x == tv.x) ? (NC + xv.x) : tv.x;
        int v1 = (xv.y == tv.y) ? (NC + xv.y) : tv.y;
        int v2 = (xv.z == tv.z) ? (NC + xv.z) : tv.z;
        int v3 = (xv.w == tv.w) ? (NC + xv.w) : tv.w;
        s_h[((u0 >> 2) << 10) | lanebase | (u0 & 3)] += 1;
        s_h[((v0 >> 2) << 10) | lanebase | (v0 & 3)] += 1;
        s_h[((u1 >> 2) << 10) | lanebase | (u1 & 3)] += 1;
        s_h[((v1 >> 2) << 10) | lanebase | (v1 & 3)] += 1;
        s_h[((u2 >> 2) << 10) | lanebase | (u2 & 3)] += 1;
        s_h[((v2 >> 2) << 10) | lanebase | (v2 & 3)] += 1;
        s_h[((u3 >> 2) << 10) | lanebase | (u3 & 3)] += 1;
        s_h[((v3 >> 2) << 10) | lanebase | (v3 & 3)] += 1;
    }
    __syncthreads();

    // flush: thread c sums bin c across all 256 thread-columns.
    // threads c..c+3 read the SAME 256 dwords (broadcast), each extracting its byte lane.
    for (int c = tid; c < NBIN; c += NT) {
        const unsigned int* row = (const unsigned int*)(s_h + ((c >> 2) << 10));
        const unsigned int mask = 1u << (8 * (c & 3));
        unsigned int s = 0;
#pragma unroll 16
        for (int k = 0; k < 256; ++k) {
#if __has_builtin(__builtin_amdgcn_udot4)
            s = __builtin_amdgcn_udot4(row[k], mask, s, false);
#else
            s += (row[k] >> (8 * (c & 3))) & 0xffu;
#endif
        }
        atomicAdd(&g_hist[b * NBIN + c], (int)s);
    }
}

__global__ __launch_bounds__(64) void finalize_kernel(const int* __restrict__ g_hist,
                                                      const float* __restrict__ smooth,
                                                      float* __restrict__ out) {
    const int b = blockIdx.x;
    const int lane = threadIdx.x;  // 0..63
    const float s = smooth[0];
    float acc = 0.0f;
    for (int c = lane; c < NC; c += 64) {
        float un = (float)g_hist[b * NBIN + c];
        float in = (float)g_hist[b * NBIN + NC + c];
        acc += (in + s) / (un + s);
    }
#pragma unroll
    for (int off = 32; off > 0; off >>= 1)
        acc += __shfl_down(acc, off, 64);
    if (lane == 0) out[b] = acc / (float)NC;
}

extern "C" void kernel_launch(void* const* d_in, const int* in_sizes, int n_in,
                              void* d_out, int out_size, void* d_ws, size_t ws_size,
                              hipStream_t stream) {
    const int* x = (const int*)d_in[0];
    const int* t = (const int*)d_in[1];
    const float* smooth = (const float*)d_in[2];
    float* out = (float*)d_out;

    int* g_hist = (int*)d_ws;

    hipMemsetAsync(d_ws, 0, NB * NBIN * sizeof(int), stream);

    dim3 grid(HW / PIX_PER_BLOCK, NB);  // 64 x 32 = 2048 blocks
    hist_kernel<<<grid, NT, 0, stream>>>(x, t, g_hist);
    finalize_kernel<<<NB, 64, 0, stream>>>(g_hist, smooth, out);
}